// Round 3
// baseline (4105.617 us; speedup 1.0000x reference)
//
#include <hip/hip_runtime.h>

typedef unsigned int u32;
typedef unsigned short u16;

#define NN 100000
#define NE 3200000
#define DF 64
#define ALPHA 0.1f
#define BETA 0.9f
#define K_STEPS 10
#define NCHUNK 4           // 4 feature chunks of 16
#define SCAN_B 1024
#define NB_SCAN ((NN + SCAN_B - 1) / SCAN_B)   // 98

// bf16 round-to-nearest-even, returns 16-bit pattern (incl sign bit)
__device__ __forceinline__ u32 rne_bf16(float f) {
    u32 u = __float_as_uint(f);
    return (u + 0x7FFFu + ((u >> 16) & 1u)) >> 16;
}
__device__ __forceinline__ float bf_lo(u32 w) { return __uint_as_float(w << 16); }
__device__ __forceinline__ float bf_hi(u32 w) { return __uint_as_float(w & 0xFFFF0000u); }

// ---- CSR build ----------------------------------------------------------

__global__ void hist_rows(const int* __restrict__ row, int* __restrict__ cnt) {
    int e = blockIdx.x * blockDim.x + threadIdx.x;
    if (e < NE) atomicAdd(&cnt[row[e]], 1);
}

__global__ void scan_blocks(const int* __restrict__ cnt, int* __restrict__ rp,
                            int* __restrict__ bsum) {
    __shared__ int s[SCAN_B];
    int i = blockIdx.x * SCAN_B + threadIdx.x;
    int v = (i < NN) ? cnt[i] : 0;
    s[threadIdx.x] = v;
    __syncthreads();
    for (int off = 1; off < SCAN_B; off <<= 1) {
        int t = (threadIdx.x >= off) ? s[threadIdx.x - off] : 0;
        __syncthreads();
        s[threadIdx.x] += t;
        __syncthreads();
    }
    if (i < NN) rp[i] = s[threadIdx.x] - v;          // exclusive
    if (threadIdx.x == SCAN_B - 1) bsum[blockIdx.x] = s[SCAN_B - 1];
}

__global__ void scan_sums(int* __restrict__ bsum) {
    if (blockIdx.x == 0 && threadIdx.x == 0) {
        int run = 0;
        for (int b = 0; b < NB_SCAN; ++b) { int v = bsum[b]; bsum[b] = run; run += v; }
    }
}

__global__ void add_offsets(int* __restrict__ rp, const int* __restrict__ bsum) {
    int i = blockIdx.x * SCAN_B + threadIdx.x;
    if (i < NN) rp[i] += bsum[blockIdx.x];
}

// fill packed CSR: edge word = (col << 15) | bf16_rne(w)[14:0]  (w >= 0)
// mutates rp so that afterwards rp[r] = end of row r
__global__ void fill_csr(const int* __restrict__ row, const int* __restrict__ col,
                         const float* __restrict__ w, int* __restrict__ rp,
                         u32* __restrict__ edges) {
    int e = blockIdx.x * blockDim.x + threadIdx.x;
    if (e < NE) {
        int r = row[e];
        int pos = atomicAdd(&rp[r], 1);
        u32 w15 = rne_bf16(w[e]) & 0x7FFFu;
        edges[pos] = ((u32)col[e] << 15) | w15;
    }
}

// ---- transpose x into chunk-major bf16: xc[c][node][16] -----------------
__global__ void transpose_x(const float* __restrict__ x, u16* __restrict__ xc) {
    int node = blockIdx.x * blockDim.x + threadIdx.x;
    int c = blockIdx.y;
    if (node >= NN) return;
    const float4* src = (const float4*)(x + (size_t)node * DF + c * 16);
    float4 a = src[0], b = src[1], d = src[2], e = src[3];
    u32 r0 = rne_bf16(a.x) | (rne_bf16(a.y) << 16);
    u32 r1 = rne_bf16(a.z) | (rne_bf16(a.w) << 16);
    u32 r2 = rne_bf16(b.x) | (rne_bf16(b.y) << 16);
    u32 r3 = rne_bf16(b.z) | (rne_bf16(b.w) << 16);
    u32 r4 = rne_bf16(d.x) | (rne_bf16(d.y) << 16);
    u32 r5 = rne_bf16(d.z) | (rne_bf16(d.w) << 16);
    u32 r6 = rne_bf16(e.x) | (rne_bf16(e.y) << 16);
    u32 r7 = rne_bf16(e.z) | (rne_bf16(e.w) << 16);
    uint4* dst = (uint4*)(xc + (size_t)c * NN * 16 + (size_t)node * 16);
    dst[0] = make_uint4(r0, r1, r2, r3);
    dst[1] = make_uint4(r4, r5, r6, r7);
}

// ---- propagation: chunked pull-mode SpMM, 2 lanes/node, 4 chunk passes --
// hn[c][r][:] = BETA * sum_e w*h[c][col][:] + ALPHA * xc[c][r][:]
__global__ void gather_chunk(const int* __restrict__ rp, const u32* __restrict__ edges,
                             const u16* __restrict__ hc, const u16* __restrict__ xc,
                             u16* __restrict__ hn, float* __restrict__ outf,
                             int final_step) {
    int p = blockIdx.y;                       // chunk index 0..3
    int t = blockIdx.x * blockDim.x + threadIdx.x;
    int node = t >> 1;
    int half = t & 1;                         // which 8 features of the 16
    if (node >= NN) return;
    int start = (node == 0) ? 0 : rp[node - 1];
    int end = rp[node];
    const u16* hbase = hc + (size_t)p * (NN * 16) + half * 8;

    float a0=0.f,a1=0.f,a2=0.f,a3=0.f,a4=0.f,a5=0.f,a6=0.f,a7=0.f;
    for (int e = start; e < end; ++e) {
        u32 ew = __builtin_nontemporal_load(edges + e);
        int c = ew >> 15;
        float wv = __uint_as_float((ew & 0x7FFFu) << 16);
        uint4 hv = *(const uint4*)(hbase + (size_t)c * 16);
        a0 += wv * bf_lo(hv.x); a1 += wv * bf_hi(hv.x);
        a2 += wv * bf_lo(hv.y); a3 += wv * bf_hi(hv.y);
        a4 += wv * bf_lo(hv.z); a5 += wv * bf_hi(hv.z);
        a6 += wv * bf_lo(hv.w); a7 += wv * bf_hi(hv.w);
    }
    uint4 xv = *(const uint4*)(xc + (size_t)p * (NN * 16) + (size_t)node * 16 + half * 8);
    float o0 = BETA * a0 + ALPHA * bf_lo(xv.x);
    float o1 = BETA * a1 + ALPHA * bf_hi(xv.x);
    float o2 = BETA * a2 + ALPHA * bf_lo(xv.y);
    float o3 = BETA * a3 + ALPHA * bf_hi(xv.y);
    float o4 = BETA * a4 + ALPHA * bf_lo(xv.z);
    float o5 = BETA * a5 + ALPHA * bf_hi(xv.z);
    float o6 = BETA * a6 + ALPHA * bf_lo(xv.w);
    float o7 = BETA * a7 + ALPHA * bf_hi(xv.w);

    if (!final_step) {
        u32 r0 = rne_bf16(o0) | (rne_bf16(o1) << 16);
        u32 r1 = rne_bf16(o2) | (rne_bf16(o3) << 16);
        u32 r2 = rne_bf16(o4) | (rne_bf16(o5) << 16);
        u32 r3 = rne_bf16(o6) | (rne_bf16(o7) << 16);
        *(uint4*)(hn + (size_t)p * (NN * 16) + (size_t)node * 16 + half * 8) =
            make_uint4(r0, r1, r2, r3);
    } else {
        float* dst = outf + (size_t)node * DF + p * 16 + half * 8;
        *(float4*)dst = make_float4(o0, o1, o2, o3);
        *((float4*)dst + 1) = make_float4(o4, o5, o6, o7);
    }
}

// ---- launch -------------------------------------------------------------

extern "C" void kernel_launch(void* const* d_in, const int* in_sizes, int n_in,
                              void* d_out, int out_size, void* d_ws, size_t ws_size,
                              hipStream_t stream) {
    const float* x    = (const float*)d_in[0];
    const int*   erow = (const int*)  d_in[1];
    const int*   ecol = (const int*)  d_in[2];
    const float* ew   = (const float*)d_in[3];
    float* out = (float*)d_out;

    char* ws = (char*)d_ws;
    u32* edges = (u32*)(ws);                      // 12,800,000 B
    u16* xc    = (u16*)(ws + 12800000);           // 12,800,000 B
    u16* hA    = (u16*)(ws + 25600000);           // 12,800,000 B
    u16* hB    = (u16*)(ws + 38400000);           // 12,800,000 B
    int* cnt   = (int*)(ws + 51200000);           //    400,000 B
    int* rp    = (int*)(ws + 51600000);           //    400,000 B
    int* bsum  = (int*)(ws + 52000000);           //        512 B

    dim3 blk(256);
    dim3 gE((NE + 255) / 256);                    // 12500 blocks
    dim3 gScan(NB_SCAN);
    dim3 gT((NN + 255) / 256, NCHUNK);
    dim3 gG((NN * 2 + 255) / 256, NCHUNK);        // 782 x 4 blocks

    // CSR build (packed 4B edges) + x transpose to chunked bf16
    hipMemsetAsync(cnt, 0, NN * sizeof(int), stream);
    hist_rows<<<gE, blk, 0, stream>>>(erow, cnt);
    scan_blocks<<<gScan, SCAN_B, 0, stream>>>(cnt, rp, bsum);
    scan_sums<<<1, 64, 0, stream>>>(bsum);
    add_offsets<<<gScan, SCAN_B, 0, stream>>>(rp, bsum);
    fill_csr<<<gE, blk, 0, stream>>>(erow, ecol, ew, rp, edges);
    transpose_x<<<gT, blk, 0, stream>>>(x, xc);

    // K propagation steps; h_0 = x (read from xc), last step writes f32 out
    for (int k = 0; k < K_STEPS; ++k) {
        const u16* hcur = (k == 0) ? xc : ((k & 1) ? hA : hB);
        u16* hnext = (k & 1) ? hB : hA;
        int fin = (k == K_STEPS - 1);
        gather_chunk<<<gG, blk, 0, stream>>>(rp, edges, hcur, xc,
                                             fin ? nullptr : hnext,
                                             fin ? out : nullptr, fin);
    }
}

// Round 4
// 1859.381 us; speedup vs baseline: 2.2081x; 2.2081x over previous
//
#include <hip/hip_runtime.h>

typedef unsigned int u32;
typedef unsigned short u16;

#define NN 100000
#define NE 3200000
#define DF 64
#define ALPHA 0.1f
#define BETA 0.9f
#define K_STEPS 10
#define NSEG 8
#define SEGW (NN / NSEG)          // 12500 cols per segment
#define NKEY (NN * NSEG)          // 800000 buckets
#define SCAN_B 1024
#define NB2 ((NKEY + SCAN_B - 1) / SCAN_B)   // 782

// bf16 round-to-nearest-even -> 16-bit pattern
__device__ __forceinline__ u32 rne_bf16(float f) {
    u32 u = __float_as_uint(f);
    return (u + 0x7FFFu + ((u >> 16) & 1u)) >> 16;
}
__device__ __forceinline__ float bf_lo(u32 w) { return __uint_as_float(w << 16); }
__device__ __forceinline__ float bf_hi(u32 w) { return __uint_as_float(w & 0xFFFF0000u); }

// ---- CSR build, key = row*8 + col/12500 ---------------------------------

__global__ void hist_keys(const int* __restrict__ row, const int* __restrict__ col,
                          int* __restrict__ cnt) {
    int e = blockIdx.x * blockDim.x + threadIdx.x;
    if (e < NE) {
        int key = row[e] * NSEG + col[e] / SEGW;
        atomicAdd(&cnt[key], 1);
    }
}

// in-place-safe exclusive scan per block (reads before writes), block totals out
__global__ void scan_blocks(const int* __restrict__ cnt, int* __restrict__ rp,
                            int* __restrict__ bsum) {
    __shared__ int s[SCAN_B];
    int i = blockIdx.x * SCAN_B + threadIdx.x;
    int v = (i < NKEY) ? cnt[i] : 0;
    s[threadIdx.x] = v;
    __syncthreads();
    for (int off = 1; off < SCAN_B; off <<= 1) {
        int t = (threadIdx.x >= off) ? s[threadIdx.x - off] : 0;
        __syncthreads();
        s[threadIdx.x] += t;
        __syncthreads();
    }
    if (i < NKEY) rp[i] = s[threadIdx.x] - v;          // exclusive
    if (threadIdx.x == SCAN_B - 1) bsum[blockIdx.x] = s[SCAN_B - 1];
}

__global__ void scan_sums(int* __restrict__ bsum) {
    if (blockIdx.x == 0 && threadIdx.x == 0) {
        int run = 0;
        for (int b = 0; b < NB2; ++b) { int v = bsum[b]; bsum[b] = run; run += v; }
    }
}

__global__ void add_offsets(int* __restrict__ rp, const int* __restrict__ bsum) {
    int i = blockIdx.x * SCAN_B + threadIdx.x;
    if (i < NKEY) rp[i] += bsum[blockIdx.x];
}

// fill packed edges: word = (col << 15) | bf16(w)[14:0]  (w in [0,1], sign=0)
// afterwards rp[key] = end of bucket
__global__ void fill_csr(const int* __restrict__ row, const int* __restrict__ col,
                         const float* __restrict__ w, int* __restrict__ rp,
                         u32* __restrict__ edges) {
    int e = blockIdx.x * blockDim.x + threadIdx.x;
    if (e < NE) {
        int c = col[e];
        int key = row[e] * NSEG + c / SEGW;
        int pos = atomicAdd(&rp[key], 1);
        u32 w15 = rne_bf16(w[e]) & 0x7FFFu;
        edges[pos] = ((u32)c << 15) | w15;
    }
}

// ---- x (f32, row-major) -> bf16 rows ------------------------------------
__global__ void conv_x(const float* __restrict__ x, u32* __restrict__ h) {
    int t = blockIdx.x * blockDim.x + threadIdx.x;   // NN*8 threads, 8 feats each
    if (t >= NN * 8) return;
    const float4* src = (const float4*)(x + (size_t)t * 8);
    float4 a = src[0], b = src[1];
    uint4 o;
    o.x = rne_bf16(a.x) | (rne_bf16(a.y) << 16);
    o.y = rne_bf16(a.z) | (rne_bf16(a.w) << 16);
    o.z = rne_bf16(b.x) | (rne_bf16(b.y) << 16);
    o.w = rne_bf16(b.z) | (rne_bf16(b.w) << 16);
    *(uint4*)(h + (size_t)t * 4) = o;
}

// ---- propagation: pull SpMM, 8 lanes/node, segment-swept ----------------
// hn[r] = BETA * sum w*h[col] + ALPHA * x[r]
__global__ void gather_step(const int* __restrict__ rp, const u32* __restrict__ edges,
                            const u32* __restrict__ h, const float* __restrict__ x,
                            u32* __restrict__ hn, float* __restrict__ outf,
                            int final_step) {
    int t = blockIdx.x * blockDim.x + threadIdx.x;
    int node = t >> 3;          // 32 nodes per 256-thread block, exact fit
    int sub = t & 7;            // 8 features each

    int prev = (node == 0) ? 0 : rp[node * NSEG - 1];
    float a0=0.f,a1=0.f,a2=0.f,a3=0.f,a4=0.f,a5=0.f,a6=0.f,a7=0.f;

    for (int seg = 0; seg < NSEG; ++seg) {
        int end = rp[node * NSEG + seg];
        for (int e = prev; e < end; ++e) {
            u32 ew = __builtin_nontemporal_load(edges + e);
            int c = ew >> 15;
            float wv = __uint_as_float((ew & 0x7FFFu) << 16);
            uint4 hv = *(const uint4*)(h + ((size_t)c << 5) + (sub << 2));
            a0 += wv * bf_lo(hv.x); a1 += wv * bf_hi(hv.x);
            a2 += wv * bf_lo(hv.y); a3 += wv * bf_hi(hv.y);
            a4 += wv * bf_lo(hv.z); a5 += wv * bf_hi(hv.z);
            a6 += wv * bf_lo(hv.w); a7 += wv * bf_hi(hv.w);
        }
        prev = end;
        __syncthreads();        // keep the block's col-window in phase
    }

    const float4* xs = (const float4*)(x + (size_t)node * DF + sub * 8);
    float4 xa = xs[0], xb = xs[1];
    float o0 = BETA * a0 + ALPHA * xa.x;
    float o1 = BETA * a1 + ALPHA * xa.y;
    float o2 = BETA * a2 + ALPHA * xa.z;
    float o3 = BETA * a3 + ALPHA * xa.w;
    float o4 = BETA * a4 + ALPHA * xb.x;
    float o5 = BETA * a5 + ALPHA * xb.y;
    float o6 = BETA * a6 + ALPHA * xb.z;
    float o7 = BETA * a7 + ALPHA * xb.w;

    if (!final_step) {
        uint4 o;
        o.x = rne_bf16(o0) | (rne_bf16(o1) << 16);
        o.y = rne_bf16(o2) | (rne_bf16(o3) << 16);
        o.z = rne_bf16(o4) | (rne_bf16(o5) << 16);
        o.w = rne_bf16(o6) | (rne_bf16(o7) << 16);
        *(uint4*)(hn + ((size_t)node << 5) + (sub << 2)) = o;
    } else {
        float* dst = outf + (size_t)node * DF + sub * 8;
        *(float4*)dst = make_float4(o0, o1, o2, o3);
        *((float4*)dst + 1) = make_float4(o4, o5, o6, o7);
    }
}

// ---- launch -------------------------------------------------------------

extern "C" void kernel_launch(void* const* d_in, const int* in_sizes, int n_in,
                              void* d_out, int out_size, void* d_ws, size_t ws_size,
                              hipStream_t stream) {
    const float* x    = (const float*)d_in[0];
    const int*   erow = (const int*)  d_in[1];
    const int*   ecol = (const int*)  d_in[2];
    const float* ew   = (const float*)d_in[3];
    float* out = (float*)d_out;

    char* ws = (char*)d_ws;
    u32* edges = (u32*)(ws);                      // 12,800,000 B
    u32* hA    = (u32*)(ws + 12800000);           // 12,800,000 B
    u32* hB    = (u32*)(ws + 25600000);           // 12,800,000 B
    int* rp    = (int*)(ws + 38400000);           //  3,200,000 B (hist in-place scan)
    int* bsum  = (int*)(ws + 41600000);           //      3,128 B

    dim3 blk(256);
    dim3 gE((NE + 255) / 256);                    // 12500
    dim3 gScan(NB2);                              // 782
    dim3 gConv((NN * 8 + 255) / 256);             // 3125
    dim3 gG((NN * 8 + 255) / 256);                // 3125 (exact: 800000 threads)

    // CSR build keyed by (row, col-segment)
    hipMemsetAsync(rp, 0, NKEY * sizeof(int), stream);
    hist_keys<<<gE, blk, 0, stream>>>(erow, ecol, rp);
    scan_blocks<<<gScan, SCAN_B, 0, stream>>>(rp, rp, bsum);   // in-place safe
    scan_sums<<<1, 64, 0, stream>>>(bsum);
    add_offsets<<<gScan, SCAN_B, 0, stream>>>(rp, bsum);
    fill_csr<<<gE, blk, 0, stream>>>(erow, ecol, ew, rp, edges);
    conv_x<<<gConv, blk, 0, stream>>>(x, hA);

    // k even: hA->hB, k odd: hB->hA; k=9 reads hB, writes f32 out
    for (int k = 0; k < K_STEPS; ++k) {
        const u32* src = (k & 1) ? hB : hA;
        u32* dst = (k & 1) ? hA : hB;
        int fin = (k == K_STEPS - 1);
        gather_step<<<gG, blk, 0, stream>>>(rp, edges, src, x,
                                            fin ? nullptr : dst,
                                            fin ? out : nullptr, fin);
    }
}

// Round 5
// 1126.308 us; speedup vs baseline: 3.6452x; 1.6509x over previous
//
#include <hip/hip_runtime.h>

typedef unsigned int u32;
typedef unsigned short u16;

#define NN 100000
#define NE 3200000
#define DF 64
#define ALPHA 0.1f
#define BETA 0.9f
#define K_STEPS 10
#define NSEG 8
#define SEGW (NN / NSEG)          // 12500 cols per segment
#define NKEY (NN * NSEG)          // 800000 buckets
#define SCAN_B 1024
#define NB2 ((NKEY + SCAN_B - 1) / SCAN_B)   // 782

// bf16 round-to-nearest-even -> 16-bit pattern
__device__ __forceinline__ u32 rne_bf16(float f) {
    u32 u = __float_as_uint(f);
    return (u + 0x7FFFu + ((u >> 16) & 1u)) >> 16;
}
__device__ __forceinline__ float bf_lo(u32 w) { return __uint_as_float(w << 16); }
__device__ __forceinline__ float bf_hi(u32 w) { return __uint_as_float(w & 0xFFFF0000u); }

// ---- CSR build, key = row*8 + col/12500 ---------------------------------

__global__ void hist_keys(const int* __restrict__ row, const int* __restrict__ col,
                          int* __restrict__ cnt) {
    int e = blockIdx.x * blockDim.x + threadIdx.x;
    if (e < NE) {
        int key = row[e] * NSEG + col[e] / SEGW;
        atomicAdd(&cnt[key], 1);
    }
}

// in-place-safe exclusive scan per block, block totals out
__global__ void scan_blocks(const int* __restrict__ cnt, int* __restrict__ rp,
                            int* __restrict__ bsum) {
    __shared__ int s[SCAN_B];
    int i = blockIdx.x * SCAN_B + threadIdx.x;
    int v = (i < NKEY) ? cnt[i] : 0;
    s[threadIdx.x] = v;
    __syncthreads();
    for (int off = 1; off < SCAN_B; off <<= 1) {
        int t = (threadIdx.x >= off) ? s[threadIdx.x - off] : 0;
        __syncthreads();
        s[threadIdx.x] += t;
        __syncthreads();
    }
    if (i < NKEY) rp[i] = s[threadIdx.x] - v;          // exclusive
    if (threadIdx.x == SCAN_B - 1) bsum[blockIdx.x] = s[SCAN_B - 1];
}

// parallel exclusive scan of the 782 block sums — one 1024-thread block
__global__ void scan_sums(int* __restrict__ bsum) {
    __shared__ int s[SCAN_B];
    int i = threadIdx.x;
    int v = (i < NB2) ? bsum[i] : 0;
    s[i] = v;
    __syncthreads();
    for (int off = 1; off < SCAN_B; off <<= 1) {
        int t = (i >= off) ? s[i - off] : 0;
        __syncthreads();
        s[i] += t;
        __syncthreads();
    }
    if (i < NB2) bsum[i] = s[i] - v;                   // exclusive
}

__global__ void add_offsets(int* __restrict__ rp, const int* __restrict__ bsum) {
    int i = blockIdx.x * SCAN_B + threadIdx.x;
    if (i < NKEY) rp[i] += bsum[blockIdx.x];
}

// fill packed edges: word = (col << 15) | bf16(w)[14:0]  (w in [0,1], sign=0)
__global__ void fill_csr(const int* __restrict__ row, const int* __restrict__ col,
                         const float* __restrict__ w, int* __restrict__ rp,
                         u32* __restrict__ edges) {
    int e = blockIdx.x * blockDim.x + threadIdx.x;
    if (e < NE) {
        int c = col[e];
        int key = row[e] * NSEG + c / SEGW;
        int pos = atomicAdd(&rp[key], 1);
        u32 w15 = rne_bf16(w[e]) & 0x7FFFu;
        edges[pos] = ((u32)c << 15) | w15;
    }
}

// ---- x (f32, row-major) -> bf16 rows (serves as both h_0 and alpha-term)
__global__ void conv_x(const float* __restrict__ x, u32* __restrict__ xb) {
    int t = blockIdx.x * blockDim.x + threadIdx.x;   // NN*8 threads, 8 feats each
    if (t >= NN * 8) return;
    const float4* src = (const float4*)(x + (size_t)t * 8);
    float4 a = src[0], b = src[1];
    uint4 o;
    o.x = rne_bf16(a.x) | (rne_bf16(a.y) << 16);
    o.y = rne_bf16(a.z) | (rne_bf16(a.w) << 16);
    o.z = rne_bf16(b.x) | (rne_bf16(b.y) << 16);
    o.w = rne_bf16(b.z) | (rne_bf16(b.w) << 16);
    *(uint4*)(xb + (size_t)t * 4) = o;
}

// ---- propagation: one wave per node -------------------------------------
// lane = (slice 0..7) * 8 + (feature-group 0..7); slice s handles edges
// start+s, start+s+8, ...; fg handles features fg*8..fg*8+7 (16B of the row).
// Butterfly shfl_xor over slices reduces the 8 partials. No cross-node
// divergence (single node per wave).
__global__ __launch_bounds__(256) void
gather_step(const int* __restrict__ rp, const u32* __restrict__ edges,
            const u32* __restrict__ h, const u32* __restrict__ xb,
            u32* __restrict__ hn, float* __restrict__ outf, int final_step) {
    int lane = threadIdx.x & 63;
    int node = blockIdx.x * 4 + (threadIdx.x >> 6);
    int slice = lane >> 3;
    int fg = lane & 7;

    int base = node * NSEG;
    int start = (node == 0) ? 0 : rp[base - 1];
    int end = rp[base + NSEG - 1];

    float a0=0.f,a1=0.f,a2=0.f,a3=0.f,a4=0.f,a5=0.f,a6=0.f,a7=0.f;
    #pragma unroll 2
    for (int e = start + slice; e < end; e += 8) {
        u32 ew = __builtin_nontemporal_load(edges + e);
        u32 c = ew >> 15;
        float wv = __uint_as_float((ew & 0x7FFFu) << 16);
        const uint4 hv = *(const uint4*)(h + ((size_t)c << 5) + (fg << 2));
        a0 += wv * bf_lo(hv.x); a1 += wv * bf_hi(hv.x);
        a2 += wv * bf_lo(hv.y); a3 += wv * bf_hi(hv.y);
        a4 += wv * bf_lo(hv.z); a5 += wv * bf_hi(hv.z);
        a6 += wv * bf_lo(hv.w); a7 += wv * bf_hi(hv.w);
    }
    // reduce across the 8 slices (lanes differing in bits 3..5)
    for (int m = 8; m <= 32; m <<= 1) {
        a0 += __shfl_xor(a0, m, 64); a1 += __shfl_xor(a1, m, 64);
        a2 += __shfl_xor(a2, m, 64); a3 += __shfl_xor(a3, m, 64);
        a4 += __shfl_xor(a4, m, 64); a5 += __shfl_xor(a5, m, 64);
        a6 += __shfl_xor(a6, m, 64); a7 += __shfl_xor(a7, m, 64);
    }
    uint4 xv = *(const uint4*)(xb + ((size_t)node << 5) + (fg << 2));
    float o0 = BETA * a0 + ALPHA * bf_lo(xv.x);
    float o1 = BETA * a1 + ALPHA * bf_hi(xv.x);
    float o2 = BETA * a2 + ALPHA * bf_lo(xv.y);
    float o3 = BETA * a3 + ALPHA * bf_hi(xv.y);
    float o4 = BETA * a4 + ALPHA * bf_lo(xv.z);
    float o5 = BETA * a5 + ALPHA * bf_hi(xv.z);
    float o6 = BETA * a6 + ALPHA * bf_lo(xv.w);
    float o7 = BETA * a7 + ALPHA * bf_hi(xv.w);

    if (!final_step) {
        if (slice == 0) {
            uint4 o;
            o.x = rne_bf16(o0) | (rne_bf16(o1) << 16);
            o.y = rne_bf16(o2) | (rne_bf16(o3) << 16);
            o.z = rne_bf16(o4) | (rne_bf16(o5) << 16);
            o.w = rne_bf16(o6) | (rne_bf16(o7) << 16);
            *(uint4*)(hn + ((size_t)node << 5) + (fg << 2)) = o;
        }
    } else {
        if (slice < 2) {   // 16 lanes write the 256B f32 row contiguously
            float4 v = slice ? make_float4(o4, o5, o6, o7)
                             : make_float4(o0, o1, o2, o3);
            *(float4*)(outf + (size_t)node * DF + fg * 8 + slice * 4) = v;
        }
    }
}

// ---- launch -------------------------------------------------------------

extern "C" void kernel_launch(void* const* d_in, const int* in_sizes, int n_in,
                              void* d_out, int out_size, void* d_ws, size_t ws_size,
                              hipStream_t stream) {
    const float* x    = (const float*)d_in[0];
    const int*   erow = (const int*)  d_in[1];
    const int*   ecol = (const int*)  d_in[2];
    const float* ew   = (const float*)d_in[3];
    float* out = (float*)d_out;

    char* ws = (char*)d_ws;
    u32* edges = (u32*)(ws);                      // 12,800,000 B
    u32* xb    = (u32*)(ws + 12800000);           // 12,800,000 B (bf16 x == h_0)
    u32* hA    = (u32*)(ws + 25600000);           // 12,800,000 B
    u32* hB    = (u32*)(ws + 38400000);           // 12,800,000 B
    int* rp    = (int*)(ws + 51200000);           //  3,200,000 B
    int* bsum  = (int*)(ws + 54400000);           //      3,128 B

    dim3 blk(256);
    dim3 gE((NE + 255) / 256);                    // 12500
    dim3 gScan(NB2);                              // 782
    dim3 gConv((NN * 8 + 255) / 256);             // 3125
    dim3 gG(NN / 4);                              // 25000 blocks, 1 wave/node

    // CSR build keyed by (row, col-segment)
    hipMemsetAsync(rp, 0, NKEY * sizeof(int), stream);
    hist_keys<<<gE, blk, 0, stream>>>(erow, ecol, rp);
    scan_blocks<<<gScan, SCAN_B, 0, stream>>>(rp, rp, bsum);   // in-place safe
    scan_sums<<<1, SCAN_B, 0, stream>>>(bsum);
    add_offsets<<<gScan, SCAN_B, 0, stream>>>(rp, bsum);
    fill_csr<<<gE, blk, 0, stream>>>(erow, ecol, ew, rp, edges);
    conv_x<<<gConv, blk, 0, stream>>>(x, xb);

    // k=0 reads xb; then ping-pong hA/hB; k=9 writes f32 out
    for (int k = 0; k < K_STEPS; ++k) {
        const u32* src = (k == 0) ? xb : ((k & 1) ? hA : hB);
        u32* dst = (k & 1) ? hB : hA;
        int fin = (k == K_STEPS - 1);
        gather_step<<<gG, blk, 0, stream>>>(rp, edges, src, xb,
                                            fin ? nullptr : dst,
                                            fin ? out : nullptr, fin);
    }
}

// Round 7
// 852.243 us; speedup vs baseline: 4.8174x; 1.3216x over previous
//
#include <hip/hip_runtime.h>

typedef unsigned int u32;
typedef unsigned long long u64;
typedef u32   v4u __attribute__((ext_vector_type(4)));
typedef float v4f __attribute__((ext_vector_type(4)));

#define NN 100000
#define NE 3200000
#define DF 64
#define ALPHA 0.1f
#define BETA 0.9f
#define K_STEPS 10
#define NBKT 782              // ceil(NN/128) row buckets, 128 rows each
#define EPT 16                // edges per thread in bucket passes
#define CHUNK (256 * EPT)     // 4096 edges per block
#define NCHB ((NE + CHUNK - 1) / CHUNK)   // 782 chunks

// bf16 round-to-nearest-even -> 16-bit pattern
__device__ __forceinline__ u32 rne_bf16(float f) {
    u32 u = __float_as_uint(f);
    return (u + 0x7FFFu + ((u >> 16) & 1u)) >> 16;
}
__device__ __forceinline__ float bf_lo(u32 w) { return __uint_as_float(w << 16); }
__device__ __forceinline__ float bf_hi(u32 w) { return __uint_as_float(w & 0xFFFF0000u); }

// ---- A1: bucket histogram (LDS-privatized) ------------------------------
__global__ void bucket_hist(const int* __restrict__ row, int* __restrict__ bcnt) {
    __shared__ int s[NBKT];
    for (int i = threadIdx.x; i < NBKT; i += 256) s[i] = 0;
    __syncthreads();
    int base = blockIdx.x * CHUNK + threadIdx.x;
    #pragma unroll
    for (int j = 0; j < EPT; ++j) {
        int e = base + j * 256;
        if (e < NE) atomicAdd(&s[row[e] >> 7], 1);
    }
    __syncthreads();
    for (int i = threadIdx.x; i < NBKT; i += 256) {
        int v = s[i];
        if (v) atomicAdd(&bcnt[i], v);
    }
}

// ---- scan of 782 bucket counts -> bases + cursors (one block) -----------
__global__ void scan_buckets(const int* __restrict__ bcnt, int* __restrict__ bbase,
                             int* __restrict__ bcur) {
    __shared__ int s[1024];
    int i = threadIdx.x;
    int v = (i < NBKT) ? bcnt[i] : 0;
    s[i] = v;
    __syncthreads();
    for (int off = 1; off < 1024; off <<= 1) {
        int t = (i >= off) ? s[i - off] : 0;
        __syncthreads();
        s[i] += t;
        __syncthreads();
    }
    if (i < NBKT) { int b = s[i] - v; bbase[i] = b; bcur[i] = b; }
}

// ---- A2: scatter packed u64 entries into bucket regions -----------------
// entry = (row&127)<<32 | col<<15 | bf16(w)[14:0]
__global__ void bucket_scatter(const int* __restrict__ row, const int* __restrict__ col,
                               const float* __restrict__ w, int* __restrict__ bcur,
                               u64* __restrict__ e64) {
    __shared__ int scnt[NBKT];
    __shared__ int sbase[NBKT];
    for (int i = threadIdx.x; i < NBKT; i += 256) scnt[i] = 0;
    __syncthreads();
    int base = blockIdx.x * CHUNK + threadIdx.x;
    int rows[EPT];
    #pragma unroll
    for (int j = 0; j < EPT; ++j) {
        int e = base + j * 256;
        int r = (e < NE) ? row[e] : -1;
        rows[j] = r;
        if (r >= 0) atomicAdd(&scnt[r >> 7], 1);
    }
    __syncthreads();
    for (int i = threadIdx.x; i < NBKT; i += 256) {
        int c = scnt[i];
        sbase[i] = c ? atomicAdd(&bcur[i], c) : 0;
    }
    __syncthreads();
    for (int i = threadIdx.x; i < NBKT; i += 256) scnt[i] = 0;
    __syncthreads();
    #pragma unroll
    for (int j = 0; j < EPT; ++j) {
        int e = base + j * 256;
        int r = rows[j];
        if (r >= 0) {
            int b = r >> 7;
            int rank = atomicAdd(&scnt[b], 1);
            u32 cw = ((u32)col[e] << 15) | (rne_bf16(w[e]) & 0x7FFFu);
            e64[sbase[b] + rank] = ((u64)(r & 127) << 32) | cw;
        }
    }
}

// ---- B: per-bucket local CSR: rp + final packed u32 edges ---------------
__global__ void build_rows(const u64* __restrict__ e64, const int* __restrict__ bcnt,
                           const int* __restrict__ bbase, u32* __restrict__ edgesF,
                           int* __restrict__ rp) {
    __shared__ int rc[128];   // counts, then exclusive cursors
    __shared__ int rb[128];   // inclusive scan
    int b = blockIdx.x;
    int cnt = bcnt[b], base = bbase[b];
    if (threadIdx.x < 128) rc[threadIdx.x] = 0;
    __syncthreads();
    for (int e = threadIdx.x; e < cnt; e += 256)
        atomicAdd(&rc[(int)(e64[base + e] >> 32)], 1);
    __syncthreads();
    if (threadIdx.x < 128) rb[threadIdx.x] = rc[threadIdx.x];
    __syncthreads();
    for (int off = 1; off < 128; off <<= 1) {
        int t = (threadIdx.x < 128 && threadIdx.x >= off) ? rb[threadIdx.x - off] : 0;
        __syncthreads();
        if (threadIdx.x < 128) rb[threadIdx.x] += t;
        __syncthreads();
    }
    if (threadIdx.x < 128) {
        int r = b * 128 + threadIdx.x;
        if (r < NN) rp[r] = base + rb[threadIdx.x];      // global end offset
        rc[threadIdx.x] = rb[threadIdx.x] - rc[threadIdx.x];  // exclusive cursor
    }
    __syncthreads();
    for (int e = threadIdx.x; e < cnt; e += 256) {
        u64 ent = e64[base + e];
        int pos = atomicAdd(&rc[(int)(ent >> 32)], 1);
        edgesF[base + pos] = (u32)ent;
    }
}

// ---- x (f32) -> bf16 rows (h_0 and alpha-term) --------------------------
__global__ void conv_x(const float* __restrict__ x, u32* __restrict__ xb) {
    int t = blockIdx.x * blockDim.x + threadIdx.x;
    if (t >= NN * 8) return;
    const float4* src = (const float4*)(x + (size_t)t * 8);
    float4 a = src[0], b = src[1];
    uint4 o;
    o.x = rne_bf16(a.x) | (rne_bf16(a.y) << 16);
    o.y = rne_bf16(a.z) | (rne_bf16(a.w) << 16);
    o.z = rne_bf16(b.x) | (rne_bf16(b.y) << 16);
    o.w = rne_bf16(b.z) | (rne_bf16(b.w) << 16);
    *(uint4*)(xb + (size_t)t * 4) = o;
}

// ---- propagation: one wave per node, slice x feature-group lanes --------
__global__ __launch_bounds__(256) void
gather_step(const int* __restrict__ rp, const u32* __restrict__ edges,
            const u32* __restrict__ h, const u32* __restrict__ xb,
            u32* __restrict__ hn, float* __restrict__ outf, int final_step) {
    int lane = threadIdx.x & 63;
    int node = blockIdx.x * 4 + (threadIdx.x >> 6);
    int slice = lane >> 3;
    int fg = lane & 7;

    int start = (node == 0) ? 0 : rp[node - 1];
    int end = rp[node];

    float a0=0.f,a1=0.f,a2=0.f,a3=0.f,a4=0.f,a5=0.f,a6=0.f,a7=0.f;
    #pragma unroll 2
    for (int e = start + slice; e < end; e += 8) {
        u32 ew = __builtin_nontemporal_load(edges + e);
        u32 c = ew >> 15;
        float wv = __uint_as_float((ew & 0x7FFFu) << 16);
        const uint4 hv = *(const uint4*)(h + ((size_t)c << 5) + (fg << 2));
        a0 += wv * bf_lo(hv.x); a1 += wv * bf_hi(hv.x);
        a2 += wv * bf_lo(hv.y); a3 += wv * bf_hi(hv.y);
        a4 += wv * bf_lo(hv.z); a5 += wv * bf_hi(hv.z);
        a6 += wv * bf_lo(hv.w); a7 += wv * bf_hi(hv.w);
    }
    for (int m = 8; m <= 32; m <<= 1) {
        a0 += __shfl_xor(a0, m, 64); a1 += __shfl_xor(a1, m, 64);
        a2 += __shfl_xor(a2, m, 64); a3 += __shfl_xor(a3, m, 64);
        a4 += __shfl_xor(a4, m, 64); a5 += __shfl_xor(a5, m, 64);
        a6 += __shfl_xor(a6, m, 64); a7 += __shfl_xor(a7, m, 64);
    }
    uint4 xv = *(const uint4*)(xb + ((size_t)node << 5) + (fg << 2));
    float o0 = BETA * a0 + ALPHA * bf_lo(xv.x);
    float o1 = BETA * a1 + ALPHA * bf_hi(xv.x);
    float o2 = BETA * a2 + ALPHA * bf_lo(xv.y);
    float o3 = BETA * a3 + ALPHA * bf_hi(xv.y);
    float o4 = BETA * a4 + ALPHA * bf_lo(xv.z);
    float o5 = BETA * a5 + ALPHA * bf_hi(xv.z);
    float o6 = BETA * a6 + ALPHA * bf_lo(xv.w);
    float o7 = BETA * a7 + ALPHA * bf_hi(xv.w);

    if (!final_step) {
        if (slice == 0) {
            v4u o;
            o.x = rne_bf16(o0) | (rne_bf16(o1) << 16);
            o.y = rne_bf16(o2) | (rne_bf16(o3) << 16);
            o.z = rne_bf16(o4) | (rne_bf16(o5) << 16);
            o.w = rne_bf16(o6) | (rne_bf16(o7) << 16);
            __builtin_nontemporal_store(o, (v4u*)(hn + ((size_t)node << 5) + (fg << 2)));
        }
    } else {
        if (slice < 2) {
            v4f v;
            if (slice) { v.x = o4; v.y = o5; v.z = o6; v.w = o7; }
            else       { v.x = o0; v.y = o1; v.z = o2; v.w = o3; }
            __builtin_nontemporal_store(v, (v4f*)(outf + (size_t)node * DF + fg * 8 + slice * 4));
        }
    }
}

// ---- launch -------------------------------------------------------------

extern "C" void kernel_launch(void* const* d_in, const int* in_sizes, int n_in,
                              void* d_out, int out_size, void* d_ws, size_t ws_size,
                              hipStream_t stream) {
    const float* x    = (const float*)d_in[0];
    const int*   erow = (const int*)  d_in[1];
    const int*   ecol = (const int*)  d_in[2];
    const float* ew   = (const float*)d_in[3];
    float* out = (float*)d_out;

    char* ws = (char*)d_ws;
    u32* edgesF = (u32*)(ws);                     // 12,800,000 B final packed edges
    u32* xb     = (u32*)(ws + 12800000);          // 12,800,000 B bf16 x (= h_0)
    u32* hA     = (u32*)(ws + 25600000);          // 12,800,000 B
    u32* hB     = (u32*)(ws + 38400000);          // 12,800,000 B
    u64* e64    = (u64*)(ws + 25600000);          // 25,600,000 B — aliases hA+hB (dead before gathers)
    int* rp     = (int*)(ws + 51200000);          //    400,000 B
    int* bcnt   = (int*)(ws + 51600000);          //      3,128 B
    int* bbase  = (int*)(ws + 51604096);          //      3,128 B
    int* bcur   = (int*)(ws + 51608192);          //      3,128 B

    dim3 blk(256);
    dim3 gChunk(NCHB);                            // 782
    dim3 gConv((NN * 8 + 255) / 256);             // 3125
    dim3 gG(NN / 4);                              // 25000 blocks, 1 wave/node

    (void)hipMemsetAsync(bcnt, 0, NBKT * sizeof(int), stream);
    bucket_hist<<<gChunk, blk, 0, stream>>>(erow, bcnt);
    scan_buckets<<<1, 1024, 0, stream>>>(bcnt, bbase, bcur);
    bucket_scatter<<<gChunk, blk, 0, stream>>>(erow, ecol, ew, bcur, e64);
    build_rows<<<NBKT, blk, 0, stream>>>(e64, bcnt, bbase, edgesF, rp);
    conv_x<<<gConv, blk, 0, stream>>>(x, xb);

    // k=0 reads xb; then ping-pong hA/hB; k=9 writes f32 out
    for (int k = 0; k < K_STEPS; ++k) {
        const u32* src = (k == 0) ? xb : ((k & 1) ? hA : hB);
        u32* dst = (k & 1) ? hB : hA;
        int fin = (k == K_STEPS - 1);
        gather_step<<<gG, blk, 0, stream>>>(rp, edgesF, src, xb,
                                            fin ? nullptr : dst,
                                            fin ? out : nullptr, fin);
    }
}